// Round 9
// baseline (687.538 us; speedup 1.0000x reference)
//
#include <hip/hip_runtime.h>
#include <hip/hip_bf16.h>

#define DEVINL __device__ __forceinline__

constexpr int N  = 50000;
constexpr int E  = 600000;
constexpr int TE = E + N;      // edges + self loops
constexpr int D  = 128;
constexpr int SCAN_B = (N + 255) / 256;   // 196 blocks for hierarchical scan
constexpr int GEMM_ROWS = 64;             // 16 rows per wave, 4 waves
constexpr int GEMM_B = (N + GEMM_ROWS - 1) / GEMM_ROWS;  // 782

typedef short bf16x8 __attribute__((ext_vector_type(8)));
typedef float f32x4  __attribute__((ext_vector_type(4)));

DEVINL float lrelu(float x, float s) { return x >= 0.f ? x : s * x; }

DEVINL unsigned short f2bf(float f) {   // RNE fp32 -> bf16
    unsigned u = __float_as_uint(f);
    u += 0x7FFFu + ((u >> 16) & 1u);
    return (unsigned short)(u >> 16);
}

// ---------- W -> bf16 copy for all 3 layers (layout unchanged: Wb[o][k]) ----------
__global__ __launch_bounds__(256) void k_wb3(const float* __restrict__ W0,
                                             const float* __restrict__ W1,
                                             const float* __restrict__ W2,
                                             unsigned short* __restrict__ Wb) {
    int b = blockIdx.x;          // 192 blocks: 64 per layer
    int l = b >> 6;
    const float* W = (l == 0) ? W0 : (l == 1) ? W1 : W2;
    int t = (b & 63) * 256 + threadIdx.x;   // 0..16383
    Wb[l * 16384 + t] = f2bf(W[t]);
}

// ---------- MFMA GEMM: H[v,o] = sum_k Xbn[v,k] * W[o,k]  (bf16 inputs, fp32 acc) ----------
__global__ __launch_bounds__(256) void k_gemm(const float* __restrict__ X,
                                              const unsigned short* __restrict__ Wb,
                                              unsigned short* __restrict__ Hb16,
                                              const float* __restrict__ att,
                                              float* __restrict__ ai,
                                              float* __restrict__ aj,
                                              const float* __restrict__ ss, // scale[128], shift[128]
                                              int apply_bn) {
    int wave = threadIdx.x >> 6, lane = threadIdx.x & 63;
    int m = lane & 15, quad = lane >> 4;
    int r0 = blockIdx.x * GEMM_ROWS + wave * 16;

    // ---- A fragments for 4 K-steps ----
    bf16x8 afrag[4];
    int rowA = r0 + m;
    bool rowok = rowA < N;
    #pragma unroll
    for (int k4 = 0; k4 < 4; k4++) {
        int c0 = k4 * 32 + quad * 8;   // feature column of first element
        float v[8];
        if (rowok) {
            float4 x0 = *(const float4*)(X + (size_t)rowA * D + c0);
            float4 x1 = *(const float4*)(X + (size_t)rowA * D + c0 + 4);
            v[0] = x0.x; v[1] = x0.y; v[2] = x0.z; v[3] = x0.w;
            v[4] = x1.x; v[5] = x1.y; v[6] = x1.z; v[7] = x1.w;
            if (apply_bn) {
                #pragma unroll
                for (int j = 0; j < 8; j++)
                    v[j] = lrelu(v[j] * ss[c0 + j] + ss[128 + c0 + j], 0.1f);
            }
        } else {
            #pragma unroll
            for (int j = 0; j < 8; j++) v[j] = 0.f;
        }
        #pragma unroll
        for (int j = 0; j < 8; j++) afrag[k4][j] = (short)f2bf(v[j]);
    }

    // ---- 8 col-tiles of 16, K=128 via 4 MFMA each ----
    float pii[4] = {0.f, 0.f, 0.f, 0.f};
    float pjj[4] = {0.f, 0.f, 0.f, 0.f};
    #pragma unroll
    for (int nt = 0; nt < 8; nt++) {
        int n0 = nt * 16;
        f32x4 acc = {0.f, 0.f, 0.f, 0.f};
        const unsigned short* wrow = Wb + (size_t)(n0 + m) * D + quad * 8;
        #pragma unroll
        for (int k4 = 0; k4 < 4; k4++) {
            bf16x8 b = *(const bf16x8*)(wrow + k4 * 32);
            acc = __builtin_amdgcn_mfma_f32_16x16x32_bf16(afrag[k4], b, acc, 0, 0, 0);
        }
        float ad = att[n0 + m];
        float as = att[128 + n0 + m];
        #pragma unroll
        for (int i = 0; i < 4; i++) {
            int row = r0 + quad * 4 + i;
            if (row < N) Hb16[(size_t)row * D + n0 + m] = f2bf(acc[i]);
            pii[i] += acc[i] * ad;
            pjj[i] += acc[i] * as;
        }
    }

    // ---- reduce attention dots across the 16 lanes of each quad ----
    #pragma unroll
    for (int mask = 8; mask >= 1; mask >>= 1) {
        #pragma unroll
        for (int i = 0; i < 4; i++) {
            pii[i] += __shfl_xor(pii[i], mask);
            pjj[i] += __shfl_xor(pjj[i], mask);
        }
    }
    if (m == 0) {
        #pragma unroll
        for (int i = 0; i < 4; i++) {
            int row = r0 + quad * 4 + i;
            if (row < N) { ai[row] = pii[i]; aj[row] = pjj[i]; }
        }
    }
}

DEVINL void edge_sd(int e, const int* ei, int& s, int& d) {
    if (e < E) { s = ei[e]; d = ei[E + e]; }
    else       { s = d = e - E; }
}

// ---------- CSR build by dst (once; graph shared across layers) ----------
__global__ __launch_bounds__(256) void k_deg(const int* __restrict__ ei, int* __restrict__ deg) {
    int e = blockIdx.x * 256 + threadIdx.x;
    if (e >= TE) return;
    int s, d; edge_sd(e, ei, s, d);
    atomicAdd(deg + d, 1);
}

__global__ __launch_bounds__(256) void k_scan1(const int* __restrict__ deg, int* __restrict__ bsum) {
    __shared__ int red[256];
    int t = threadIdx.x;
    int v = blockIdx.x * 256 + t;
    red[t] = (v < N) ? deg[v] : 0;
    __syncthreads();
    #pragma unroll
    for (int off = 128; off; off >>= 1) {
        if (t < off) red[t] += red[t + off];
        __syncthreads();
    }
    if (t == 0) bsum[blockIdx.x] = red[0];
}

__global__ __launch_bounds__(256) void k_scan2(const int* __restrict__ bsum,
                                               int* __restrict__ boff, int* __restrict__ row_ptr) {
    __shared__ int sc[256];
    int t = threadIdx.x;
    int v = (t < SCAN_B) ? bsum[t] : 0;
    sc[t] = v;
    __syncthreads();
    #pragma unroll
    for (int off = 1; off < 256; off <<= 1) {
        int add = (t >= off) ? sc[t - off] : 0;
        __syncthreads();
        sc[t] += add;
        __syncthreads();
    }
    if (t < SCAN_B) boff[t] = sc[t] - v;       // exclusive
    if (t == SCAN_B - 1) row_ptr[N] = sc[t];   // total = TE
}

__global__ __launch_bounds__(256) void k_scan3(const int* __restrict__ deg,
                                               const int* __restrict__ boff,
                                               int* __restrict__ row_ptr) {
    __shared__ int sc[256];
    int t = threadIdx.x;
    int v = blockIdx.x * 256 + t;
    int d = (v < N) ? deg[v] : 0;
    sc[t] = d;
    __syncthreads();
    #pragma unroll
    for (int off = 1; off < 256; off <<= 1) {
        int add = (t >= off) ? sc[t - off] : 0;
        __syncthreads();
        sc[t] += add;
        __syncthreads();
    }
    if (v < N) row_ptr[v] = boff[blockIdx.x] + sc[t] - d;
}

// ---------- fill: only src_csr (dst implied by CSR row) ----------
__global__ __launch_bounds__(256) void k_fill(const int* __restrict__ ei,
                                              const int* __restrict__ row_ptr,
                                              int* __restrict__ fill,
                                              int* __restrict__ src_csr) {
    int e = blockIdx.x * 256 + threadIdx.x;
    if (e >= TE) return;
    int s, d; edge_sd(e, ei, s, d);
    int pos = atomicAdd(fill + d, 1);
    src_csr[row_ptr[d] + pos] = s;
}

// ---------- per-edge softmax numerator + denominator, wave per dst node ----------
// no max-subtraction: attention dots are O(0.1)
__global__ __launch_bounds__(256) void k_edge_soft(const int* __restrict__ row_ptr,
                                                   const int* __restrict__ src_csr,
                                                   const float* __restrict__ ai,
                                                   const float* __restrict__ aj,
                                                   float* __restrict__ alpha,
                                                   float* __restrict__ den) {
    int wid = threadIdx.x >> 6, lane = threadIdx.x & 63;
    int v = blockIdx.x * 4 + wid;
    if (v >= N) return;
    int beg = row_ptr[v], end = row_ptr[v + 1];
    float aiv = ai[v];                       // dst-side dot, wave-uniform
    for (int idx = beg + lane; idx < end; idx += 64) {
        int s = src_csr[idx];
        float a  = lrelu(aiv + aj[s], 0.2f);
        float ex = expf(a);
        alpha[idx] = ex;
        atomicAdd(den + s, ex);
    }
}

// ---------- per-node reciprocal of denominator ----------
__global__ __launch_bounds__(256) void k_invden(const float* __restrict__ den,
                                                float* __restrict__ invden) {
    int v = blockIdx.x * 256 + threadIdx.x;
    if (v >= N) return;
    invden[v] = 1.0f / (den[v] + 1e-16f);
}

// ---------- aggregation: wave per dst node, predicated 8-wide loop, bf16 H gather ----------
__global__ __launch_bounds__(256) void k_aggregate(const int* __restrict__ row_ptr,
                                                   const int* __restrict__ src_csr,
                                                   const float* __restrict__ alpha,
                                                   const float* __restrict__ invden,
                                                   const unsigned* __restrict__ Hu, // bf16x2 per uint
                                                   const float* __restrict__ bvec,
                                                   float* __restrict__ O) {
    int wid = threadIdx.x >> 6, lane = threadIdx.x & 63;
    int v = blockIdx.x * 4 + wid;
    if (v >= N) return;
    int beg = row_ptr[v], end = row_ptr[v + 1];   // end > beg (self loop guaranteed)
    float a0 = 0.f, a1 = 0.f;
    for (int idx = beg; idx < end; idx += 8) {
        int      s[8];
        float    w[8];
        unsigned u[8];
        #pragma unroll
        for (int t = 0; t < 8; t++) {
            int j = idx + t;
            bool act = j < end;
            int jc = act ? j : end - 1;           // clamp (self loop row non-empty)
            s[t] = src_csr[jc];
            w[t] = act ? alpha[jc] * invden[s[t]] : 0.f;
        }
        #pragma unroll
        for (int t = 0; t < 8; t++) u[t] = Hu[(size_t)s[t] * 64 + lane];
        #pragma unroll
        for (int t = 0; t < 8; t++) {
            a0 += w[t] * __uint_as_float(u[t] << 16);
            a1 += w[t] * __uint_as_float(u[t] & 0xFFFF0000u);
        }
    }
    float2 b = ((const float2*)bvec)[lane];
    a0 = fmaxf(a0 + b.x, 0.f);
    a1 = fmaxf(a1 + b.y, 0.f);
    ((float2*)(O + (size_t)v * D))[lane] = make_float2(a0, a1);
}

// ---------- BN column stats ----------
__global__ __launch_bounds__(256) void k_stats(const float* __restrict__ O,
                                               float* __restrict__ colsum, float* __restrict__ colsq) {
    int c = threadIdx.x & 127, rg = threadIdx.x >> 7;
    float s = 0.f, q = 0.f;
    for (int v = blockIdx.x * 2 + rg; v < N; v += gridDim.x * 2) {
        float val = O[(size_t)v * D + c];
        s += val;
        q += val * val;
    }
    __shared__ float ls[256], lq[256];
    ls[threadIdx.x] = s; lq[threadIdx.x] = q;
    __syncthreads();
    if (threadIdx.x < 128) {
        s = ls[threadIdx.x] + ls[threadIdx.x + 128];
        q = lq[threadIdx.x] + lq[threadIdx.x + 128];
        atomicAdd(colsum + c, s);
        atomicAdd(colsq + c, q);
    }
}

__global__ __launch_bounds__(128) void k_bnfinal(const float* __restrict__ colsum,
                                                 const float* __restrict__ colsq,
                                                 const float* __restrict__ g,
                                                 const float* __restrict__ be,
                                                 float* __restrict__ ss) {
    int c = threadIdx.x;
    float mean = colsum[c] / (float)N;
    float var  = colsq[c] / (float)N - mean * mean;
    float scale = g[c] * rsqrtf(var + 1e-5f);
    ss[c] = scale;
    ss[128 + c] = be[c] - mean * scale;
}

// ---------- decoder ----------
__global__ __launch_bounds__(256) void k_T(const float* __restrict__ P1, const float* __restrict__ P2,
                                           float* __restrict__ T) {
    int t = blockIdx.x * 256 + threadIdx.x;
    if (t >= 128 * 64) return;
    int i = t >> 6, d = t & 63;
    float s = 0.f;
    #pragma unroll 8
    for (int k = 0; k < 64; k++) s += P1[i * 64 + k] * P2[k * 64 + d];
    T[t] = s;
}

__global__ __launch_bounds__(256) void k_M(const float* __restrict__ T, const float* __restrict__ P1,
                                           float* __restrict__ M) {
    int t = blockIdx.x * 256 + threadIdx.x;
    if (t >= 128 * 128) return;
    int i = t >> 7, j = t & 127;
    float s = 0.f;
    #pragma unroll 8
    for (int d = 0; d < 64; d++) s += T[i * 64 + d] * P1[j * 64 + d];
    M[t] = s;
}

__global__ __launch_bounds__(128) void k_pred(const float* __restrict__ O,
                                              const float* __restrict__ ss,
                                              const int* __restrict__ drug,
                                              const float* __restrict__ M,
                                              float* __restrict__ out) {
    int b = blockIdx.x, i = threadIdx.x;
    __shared__ float av[128], bv[128];
    int ia = drug[b * 2] - 1, ib = drug[b * 2 + 1] - 1;
    float sc = ss[i], sh = ss[128 + i];
    av[i] = lrelu(O[(size_t)ia * D + i] * sc + sh, 0.1f);
    bv[i] = lrelu(O[(size_t)ib * D + i] * sc + sh, 0.1f);
    __syncthreads();
    float u = 0.f;
    #pragma unroll 8
    for (int j = 0; j < 128; j++) u += M[i * 128 + j] * bv[j];
    float val = av[i] * u;
    #pragma unroll
    for (int off = 32; off; off >>= 1) val += __shfl_down(val, off);
    __shared__ float red[2];
    if ((i & 63) == 0) red[i >> 6] = val;
    __syncthreads();
    if (i == 0) out[b] = red[0] + red[1];
}

extern "C" void kernel_launch(void* const* d_in, const int* in_sizes, int n_in,
                              void* d_out, int out_size, void* d_ws, size_t ws_size,
                              hipStream_t stream) {
    const float* x    = (const float*)d_in[0];
    const int*   ei   = (const int*)  d_in[1];
    const int*   drug = (const int*)  d_in[2];
    const float* W[3]   = {(const float*)d_in[3], (const float*)d_in[8],  (const float*)d_in[13]};
    const float* att[3] = {(const float*)d_in[4], (const float*)d_in[9],  (const float*)d_in[14]};
    const float* bb[3]  = {(const float*)d_in[5], (const float*)d_in[10], (const float*)d_in[15]};
    const float* gg[3]  = {(const float*)d_in[6], (const float*)d_in[11], (const float*)d_in[16]};
    const float* be[3]  = {(const float*)d_in[7], (const float*)d_in[12], (const float*)d_in[17]};
    const float* P1 = (const float*)d_in[18];
    const float* P2 = (const float*)d_in[19];

    float* ws = (float*)d_ws;
    size_t o_H      = 0;                     // bf16 H: N*D ushorts = N*64 floats
    size_t o_O      = o_H + (size_t)N * 64;
    size_t o_ai     = o_O + (size_t)N * D;
    size_t o_aj     = o_ai + N;
    size_t o_den    = o_aj + N;
    size_t o_inv    = o_den + N;
    size_t o_alpha  = o_inv + N;
    size_t o_deg    = o_alpha + TE;    // int
    size_t o_fill   = o_deg + N;       // int
    size_t o_rowptr = o_fill + N;      // int, N+1 (pad 8)
    size_t o_src    = o_rowptr + N + 8;// int, TE
    size_t o_bsum   = o_src + TE;      // int, SCAN_B (pad to 256)
    size_t o_boff   = o_bsum + 256;    // int, SCAN_B (pad to 256)
    size_t o_colsum = o_boff + 256;    // 128
    size_t o_colsq  = o_colsum + 128;  // 128
    size_t o_ss     = o_colsq + 128;   // 256
    size_t o_T      = o_ss + 256;      // 128*64
    size_t o_Mm     = o_T + 128 * 64;  // 128*128
    size_t o_Wb     = o_Mm + 128 * 128;// 3*16384 ushorts = 24576 floats

    unsigned short* Hb16 = (unsigned short*)(ws + o_H);
    unsigned*       Hu   = (unsigned*)(ws + o_H);
    float*    Ob    = ws + o_O;
    float*    ai    = ws + o_ai;
    float*    aj    = ws + o_aj;
    float*    den   = ws + o_den;
    float*    inv   = ws + o_inv;
    float*    alpha = ws + o_alpha;
    int*      deg   = (int*)(ws + o_deg);
    int*      fill  = (int*)(ws + o_fill);
    int*      rowp  = (int*)(ws + o_rowptr);
    int*      srcc  = (int*)(ws + o_src);
    int*      bsum  = (int*)(ws + o_bsum);
    int*      boff  = (int*)(ws + o_boff);
    float*    csum  = ws + o_colsum;
    float*    csq   = ws + o_colsq;
    float*    ss    = ws + o_ss;
    float*    Tm    = ws + o_T;
    float*    Mm    = ws + o_Mm;
    unsigned short* Wb = (unsigned short*)(ws + o_Wb);

    const int EB = (TE + 255) / 256;
    const int NB4 = (N + 3) / 4;

    // ---- CSR by dst ----
    hipMemsetAsync(deg, 0, (size_t)N * 4, stream);
    k_deg<<<EB, 256, 0, stream>>>(ei, deg);
    k_scan1<<<SCAN_B, 256, 0, stream>>>(deg, bsum);
    k_scan2<<<1, 256, 0, stream>>>(bsum, boff, rowp);
    k_scan3<<<SCAN_B, 256, 0, stream>>>(deg, boff, rowp);
    hipMemsetAsync(fill, 0, (size_t)N * 4, stream);
    k_fill<<<EB, 256, 0, stream>>>(ei, rowp, fill, srcc);

    // ---- W bf16 copies (one launch) ----
    k_wb3<<<192, 256, 0, stream>>>(W[0], W[1], W[2], Wb);

    // ---- 3 GAT layers ----
    for (int l = 0; l < 3; l++) {
        const float* Xin = (l == 0) ? x : Ob;
        k_gemm<<<GEMM_B, 256, 0, stream>>>(Xin, Wb + l * 16384, Hb16, att[l], ai, aj, ss, l > 0 ? 1 : 0);
        hipMemsetAsync(den, 0, (size_t)N * 4, stream);
        k_edge_soft<<<NB4, 256, 0, stream>>>(rowp, srcc, ai, aj, alpha, den);
        k_invden<<<SCAN_B, 256, 0, stream>>>(den, inv);
        k_aggregate<<<NB4, 256, 0, stream>>>(rowp, srcc, alpha, inv, Hu, bb[l], Ob);
        hipMemsetAsync(csum, 0, 256 * 4, stream);            // colsum + colsq
        k_stats<<<256, 256, 0, stream>>>(Ob, csum, csq);
        k_bnfinal<<<1, 128, 0, stream>>>(csum, csq, gg[l], be[l], ss);
    }

    // ---- decoder ----
    k_T<<<32, 256, 0, stream>>>(P1, P2, Tm);
    k_M<<<64, 256, 0, stream>>>(Tm, P1, Mm);
    k_pred<<<1024, 128, 0, stream>>>(Ob, ss, drug, Mm, (float*)d_out);
}

// Round 10
// 605.562 us; speedup vs baseline: 1.1354x; 1.1354x over previous
//
#include <hip/hip_runtime.h>
#include <hip/hip_bf16.h>

#define DEVINL __device__ __forceinline__

constexpr int N  = 50000;
constexpr int E  = 600000;
constexpr int TE = E + N;      // edges + self loops
constexpr int D  = 128;
constexpr int SCAN_B = (N + 255) / 256;   // 196 blocks for hierarchical scan
constexpr int GEMM_ROWS = 64;             // 16 rows per wave, 4 waves
constexpr int GEMM_B = (N + GEMM_ROWS - 1) / GEMM_ROWS;  // 782

typedef short bf16x8 __attribute__((ext_vector_type(8)));
typedef float f32x4  __attribute__((ext_vector_type(4)));

DEVINL float lrelu(float x, float s) { return x >= 0.f ? x : s * x; }

DEVINL unsigned short f2bf(float f) {   // RNE fp32 -> bf16
    unsigned u = __float_as_uint(f);
    u += 0x7FFFu + ((u >> 16) & 1u);
    return (unsigned short)(u >> 16);
}

// ---------- W -> bf16 copy for all 3 layers (layout unchanged: Wb[o][k]) ----------
__global__ __launch_bounds__(256) void k_wb3(const float* __restrict__ W0,
                                             const float* __restrict__ W1,
                                             const float* __restrict__ W2,
                                             unsigned short* __restrict__ Wb) {
    int b = blockIdx.x;          // 192 blocks: 64 per layer
    int l = b >> 6;
    const float* W = (l == 0) ? W0 : (l == 1) ? W1 : W2;
    int t = (b & 63) * 256 + threadIdx.x;   // 0..16383
    Wb[l * 16384 + t] = f2bf(W[t]);
}

// ---------- MFMA GEMM: H[v,o] = sum_k Xbn[v,k] * W[o,k]  (bf16 inputs, fp32 acc) ----------
__global__ __launch_bounds__(256) void k_gemm(const float* __restrict__ X,
                                              const unsigned short* __restrict__ Wb,
                                              unsigned short* __restrict__ Hb16,
                                              const float* __restrict__ att,
                                              float* __restrict__ ai,
                                              float* __restrict__ aj,
                                              const float* __restrict__ ss, // scale[128], shift[128]
                                              int apply_bn) {
    int wave = threadIdx.x >> 6, lane = threadIdx.x & 63;
    int m = lane & 15, quad = lane >> 4;
    int r0 = blockIdx.x * GEMM_ROWS + wave * 16;

    // ---- A fragments for 4 K-steps ----
    bf16x8 afrag[4];
    int rowA = r0 + m;
    bool rowok = rowA < N;
    #pragma unroll
    for (int k4 = 0; k4 < 4; k4++) {
        int c0 = k4 * 32 + quad * 8;   // feature column of first element
        float v[8];
        if (rowok) {
            float4 x0 = *(const float4*)(X + (size_t)rowA * D + c0);
            float4 x1 = *(const float4*)(X + (size_t)rowA * D + c0 + 4);
            v[0] = x0.x; v[1] = x0.y; v[2] = x0.z; v[3] = x0.w;
            v[4] = x1.x; v[5] = x1.y; v[6] = x1.z; v[7] = x1.w;
            if (apply_bn) {
                #pragma unroll
                for (int j = 0; j < 8; j++)
                    v[j] = lrelu(v[j] * ss[c0 + j] + ss[128 + c0 + j], 0.1f);
            }
        } else {
            #pragma unroll
            for (int j = 0; j < 8; j++) v[j] = 0.f;
        }
        #pragma unroll
        for (int j = 0; j < 8; j++) afrag[k4][j] = (short)f2bf(v[j]);
    }

    // ---- 8 col-tiles of 16, K=128 via 4 MFMA each ----
    float pii[4] = {0.f, 0.f, 0.f, 0.f};
    float pjj[4] = {0.f, 0.f, 0.f, 0.f};
    #pragma unroll
    for (int nt = 0; nt < 8; nt++) {
        int n0 = nt * 16;
        f32x4 acc = {0.f, 0.f, 0.f, 0.f};
        const unsigned short* wrow = Wb + (size_t)(n0 + m) * D + quad * 8;
        #pragma unroll
        for (int k4 = 0; k4 < 4; k4++) {
            bf16x8 b = *(const bf16x8*)(wrow + k4 * 32);
            acc = __builtin_amdgcn_mfma_f32_16x16x32_bf16(afrag[k4], b, acc, 0, 0, 0);
        }
        float ad = att[n0 + m];
        float as = att[128 + n0 + m];
        #pragma unroll
        for (int i = 0; i < 4; i++) {
            int row = r0 + quad * 4 + i;
            if (row < N) Hb16[(size_t)row * D + n0 + m] = f2bf(acc[i]);
            pii[i] += acc[i] * ad;
            pjj[i] += acc[i] * as;
        }
    }

    // ---- reduce attention dots across the 16 lanes of each quad ----
    #pragma unroll
    for (int mask = 8; mask >= 1; mask >>= 1) {
        #pragma unroll
        for (int i = 0; i < 4; i++) {
            pii[i] += __shfl_xor(pii[i], mask);
            pjj[i] += __shfl_xor(pjj[i], mask);
        }
    }
    if (m == 0) {
        #pragma unroll
        for (int i = 0; i < 4; i++) {
            int row = r0 + quad * 4 + i;
            if (row < N) { ai[row] = pii[i]; aj[row] = pjj[i]; }
        }
    }
}

DEVINL void edge_sd(int e, const int* ei, int& s, int& d) {
    if (e < E) { s = ei[e]; d = ei[E + e]; }
    else       { s = d = e - E; }
}

// ---------- CSR build by dst (once; graph shared across layers) ----------
__global__ __launch_bounds__(256) void k_deg(const int* __restrict__ ei, int* __restrict__ deg) {
    int e = blockIdx.x * 256 + threadIdx.x;
    if (e >= TE) return;
    int s, d; edge_sd(e, ei, s, d);
    atomicAdd(deg + d, 1);
}

__global__ __launch_bounds__(256) void k_scan1(const int* __restrict__ deg, int* __restrict__ bsum) {
    __shared__ int red[256];
    int t = threadIdx.x;
    int v = blockIdx.x * 256 + t;
    red[t] = (v < N) ? deg[v] : 0;
    __syncthreads();
    #pragma unroll
    for (int off = 128; off; off >>= 1) {
        if (t < off) red[t] += red[t + off];
        __syncthreads();
    }
    if (t == 0) bsum[blockIdx.x] = red[0];
}

__global__ __launch_bounds__(256) void k_scan2(const int* __restrict__ bsum,
                                               int* __restrict__ boff, int* __restrict__ row_ptr) {
    __shared__ int sc[256];
    int t = threadIdx.x;
    int v = (t < SCAN_B) ? bsum[t] : 0;
    sc[t] = v;
    __syncthreads();
    #pragma unroll
    for (int off = 1; off < 256; off <<= 1) {
        int add = (t >= off) ? sc[t - off] : 0;
        __syncthreads();
        sc[t] += add;
        __syncthreads();
    }
    if (t < SCAN_B) boff[t] = sc[t] - v;       // exclusive
    if (t == SCAN_B - 1) row_ptr[N] = sc[t];   // total = TE
}

__global__ __launch_bounds__(256) void k_scan3(const int* __restrict__ deg,
                                               const int* __restrict__ boff,
                                               int* __restrict__ row_ptr) {
    __shared__ int sc[256];
    int t = threadIdx.x;
    int v = blockIdx.x * 256 + t;
    int d = (v < N) ? deg[v] : 0;
    sc[t] = d;
    __syncthreads();
    #pragma unroll
    for (int off = 1; off < 256; off <<= 1) {
        int add = (t >= off) ? sc[t - off] : 0;
        __syncthreads();
        sc[t] += add;
        __syncthreads();
    }
    if (v < N) row_ptr[v] = boff[blockIdx.x] + sc[t] - d;
}

// ---------- fill: only src_csr (dst implied by CSR row) ----------
__global__ __launch_bounds__(256) void k_fill(const int* __restrict__ ei,
                                              const int* __restrict__ row_ptr,
                                              int* __restrict__ fill,
                                              int* __restrict__ src_csr) {
    int e = blockIdx.x * 256 + threadIdx.x;
    if (e >= TE) return;
    int s, d; edge_sd(e, ei, s, d);
    int pos = atomicAdd(fill + d, 1);
    src_csr[row_ptr[d] + pos] = s;
}

// ---------- per-edge softmax numerator + denominator, wave per dst node ----------
// no max-subtraction: attention dots are O(0.1)
__global__ __launch_bounds__(256) void k_edge_soft(const int* __restrict__ row_ptr,
                                                   const int* __restrict__ src_csr,
                                                   const float* __restrict__ ai,
                                                   const float* __restrict__ aj,
                                                   float* __restrict__ alpha,
                                                   float* __restrict__ den) {
    int wid = threadIdx.x >> 6, lane = threadIdx.x & 63;
    int v = blockIdx.x * 4 + wid;
    if (v >= N) return;
    int beg = row_ptr[v], end = row_ptr[v + 1];
    float aiv = ai[v];                       // dst-side dot, wave-uniform
    for (int idx = beg + lane; idx < end; idx += 64) {
        int s = src_csr[idx];
        float a  = lrelu(aiv + aj[s], 0.2f);
        float ex = expf(a);
        alpha[idx] = ex;
        atomicAdd(den + s, ex);
    }
}

// ---------- per-node reciprocal of denominator ----------
__global__ __launch_bounds__(256) void k_invden(const float* __restrict__ den,
                                                float* __restrict__ invden) {
    int v = blockIdx.x * 256 + threadIdx.x;
    if (v >= N) return;
    invden[v] = 1.0f / (den[v] + 1e-16f);
}

// ---------- aggregation: wave per dst node, 8-edge unroll + scalar tail, bf16 H gather ----------
// NOTE: predicated/clamped 8-slot variant measured WORSE (66 vs 43.5 us, R9) —
// dependent cndmask before each gather + duplicated pad gathers kill MLP. Keep this form.
__global__ __launch_bounds__(256) void k_aggregate(const int* __restrict__ row_ptr,
                                                   const int* __restrict__ src_csr,
                                                   const float* __restrict__ alpha,
                                                   const float* __restrict__ invden,
                                                   const unsigned* __restrict__ Hu, // bf16x2 per uint
                                                   const float* __restrict__ bvec,
                                                   float* __restrict__ O) {
    int wid = threadIdx.x >> 6, lane = threadIdx.x & 63;
    int v = blockIdx.x * 4 + wid;
    if (v >= N) return;
    int beg = row_ptr[v], end = row_ptr[v + 1];
    float a0 = 0.f, a1 = 0.f;
    int idx = beg;
    for (; idx + 8 <= end; idx += 8) {
        int      s[8];
        float    w[8];
        unsigned u[8];
        #pragma unroll
        for (int t = 0; t < 8; t++) s[t] = src_csr[idx + t];
        #pragma unroll
        for (int t = 0; t < 8; t++) w[t] = alpha[idx + t] * invden[s[t]];
        #pragma unroll
        for (int t = 0; t < 8; t++) u[t] = Hu[(size_t)s[t] * 64 + lane];
        #pragma unroll
        for (int t = 0; t < 8; t++) {
            a0 += w[t] * __uint_as_float(u[t] << 16);
            a1 += w[t] * __uint_as_float(u[t] & 0xFFFF0000u);
        }
    }
    for (; idx < end; idx++) {
        int s = src_csr[idx];
        float w = alpha[idx] * invden[s];
        unsigned u = Hu[(size_t)s * 64 + lane];
        a0 += w * __uint_as_float(u << 16);
        a1 += w * __uint_as_float(u & 0xFFFF0000u);
    }
    float2 b = ((const float2*)bvec)[lane];
    a0 = fmaxf(a0 + b.x, 0.f);
    a1 = fmaxf(a1 + b.y, 0.f);
    ((float2*)(O + (size_t)v * D))[lane] = make_float2(a0, a1);
}

// ---------- BN column stats ----------
__global__ __launch_bounds__(256) void k_stats(const float* __restrict__ O,
                                               float* __restrict__ colsum, float* __restrict__ colsq) {
    int c = threadIdx.x & 127, rg = threadIdx.x >> 7;
    float s = 0.f, q = 0.f;
    for (int v = blockIdx.x * 2 + rg; v < N; v += gridDim.x * 2) {
        float val = O[(size_t)v * D + c];
        s += val;
        q += val * val;
    }
    __shared__ float ls[256], lq[256];
    ls[threadIdx.x] = s; lq[threadIdx.x] = q;
    __syncthreads();
    if (threadIdx.x < 128) {
        s = ls[threadIdx.x] + ls[threadIdx.x + 128];
        q = lq[threadIdx.x] + lq[threadIdx.x + 128];
        atomicAdd(colsum + c, s);
        atomicAdd(colsq + c, q);
    }
}

__global__ __launch_bounds__(128) void k_bnfinal(const float* __restrict__ colsum,
                                                 const float* __restrict__ colsq,
                                                 const float* __restrict__ g,
                                                 const float* __restrict__ be,
                                                 float* __restrict__ ss) {
    int c = threadIdx.x;
    float mean = colsum[c] / (float)N;
    float var  = colsq[c] / (float)N - mean * mean;
    float scale = g[c] * rsqrtf(var + 1e-5f);
    ss[c] = scale;
    ss[128 + c] = be[c] - mean * scale;
}

// ---------- decoder ----------
__global__ __launch_bounds__(256) void k_T(const float* __restrict__ P1, const float* __restrict__ P2,
                                           float* __restrict__ T) {
    int t = blockIdx.x * 256 + threadIdx.x;
    if (t >= 128 * 64) return;
    int i = t >> 6, d = t & 63;
    float s = 0.f;
    #pragma unroll 8
    for (int k = 0; k < 64; k++) s += P1[i * 64 + k] * P2[k * 64 + d];
    T[t] = s;
}

__global__ __launch_bounds__(256) void k_M(const float* __restrict__ T, const float* __restrict__ P1,
                                           float* __restrict__ M) {
    int t = blockIdx.x * 256 + threadIdx.x;
    if (t >= 128 * 128) return;
    int i = t >> 7, j = t & 127;
    float s = 0.f;
    #pragma unroll 8
    for (int d = 0; d < 64; d++) s += T[i * 64 + d] * P1[j * 64 + d];
    M[t] = s;
}

__global__ __launch_bounds__(128) void k_pred(const float* __restrict__ O,
                                              const float* __restrict__ ss,
                                              const int* __restrict__ drug,
                                              const float* __restrict__ M,
                                              float* __restrict__ out) {
    int b = blockIdx.x, i = threadIdx.x;
    __shared__ float av[128], bv[128];
    int ia = drug[b * 2] - 1, ib = drug[b * 2 + 1] - 1;
    float sc = ss[i], sh = ss[128 + i];
    av[i] = lrelu(O[(size_t)ia * D + i] * sc + sh, 0.1f);
    bv[i] = lrelu(O[(size_t)ib * D + i] * sc + sh, 0.1f);
    __syncthreads();
    float u = 0.f;
    #pragma unroll 8
    for (int j = 0; j < 128; j++) u += M[i * 128 + j] * bv[j];
    float val = av[i] * u;
    #pragma unroll
    for (int off = 32; off; off >>= 1) val += __shfl_down(val, off);
    __shared__ float red[2];
    if ((i & 63) == 0) red[i >> 6] = val;
    __syncthreads();
    if (i == 0) out[b] = red[0] + red[1];
}

extern "C" void kernel_launch(void* const* d_in, const int* in_sizes, int n_in,
                              void* d_out, int out_size, void* d_ws, size_t ws_size,
                              hipStream_t stream) {
    const float* x    = (const float*)d_in[0];
    const int*   ei   = (const int*)  d_in[1];
    const int*   drug = (const int*)  d_in[2];
    const float* W[3]   = {(const float*)d_in[3], (const float*)d_in[8],  (const float*)d_in[13]};
    const float* att[3] = {(const float*)d_in[4], (const float*)d_in[9],  (const float*)d_in[14]};
    const float* bb[3]  = {(const float*)d_in[5], (const float*)d_in[10], (const float*)d_in[15]};
    const float* gg[3]  = {(const float*)d_in[6], (const float*)d_in[11], (const float*)d_in[16]};
    const float* be[3]  = {(const float*)d_in[7], (const float*)d_in[12], (const float*)d_in[17]};
    const float* P1 = (const float*)d_in[18];
    const float* P2 = (const float*)d_in[19];

    float* ws = (float*)d_ws;
    size_t o_H      = 0;                     // bf16 H: N*D ushorts = N*64 floats
    size_t o_O      = o_H + (size_t)N * 64;
    size_t o_ai     = o_O + (size_t)N * D;
    size_t o_aj     = o_ai + N;
    size_t o_den    = o_aj + N;
    size_t o_inv    = o_den + N;
    size_t o_alpha  = o_inv + N;
    size_t o_deg    = o_alpha + TE;    // int
    size_t o_fill   = o_deg + N;       // int
    size_t o_rowptr = o_fill + N;      // int, N+1 (pad 8)
    size_t o_src    = o_rowptr + N + 8;// int, TE
    size_t o_bsum   = o_src + TE;      // int, SCAN_B (pad to 256)
    size_t o_boff   = o_bsum + 256;    // int, SCAN_B (pad to 256)
    size_t o_colsum = o_boff + 256;    // 128
    size_t o_colsq  = o_colsum + 128;  // 128
    size_t o_ss     = o_colsq + 128;   // 256
    size_t o_T      = o_ss + 256;      // 128*64
    size_t o_Mm     = o_T + 128 * 64;  // 128*128
    size_t o_Wb     = o_Mm + 128 * 128;// 3*16384 ushorts = 24576 floats

    unsigned short* Hb16 = (unsigned short*)(ws + o_H);
    unsigned*       Hu   = (unsigned*)(ws + o_H);
    float*    Ob    = ws + o_O;
    float*    ai    = ws + o_ai;
    float*    aj    = ws + o_aj;
    float*    den   = ws + o_den;
    float*    inv   = ws + o_inv;
    float*    alpha = ws + o_alpha;
    int*      deg   = (int*)(ws + o_deg);
    int*      fill  = (int*)(ws + o_fill);
    int*      rowp  = (int*)(ws + o_rowptr);
    int*      srcc  = (int*)(ws + o_src);
    int*      bsum  = (int*)(ws + o_bsum);
    int*      boff  = (int*)(ws + o_boff);
    float*    csum  = ws + o_colsum;
    float*    csq   = ws + o_colsq;
    float*    ss    = ws + o_ss;
    float*    Tm    = ws + o_T;
    float*    Mm    = ws + o_Mm;
    unsigned short* Wb = (unsigned short*)(ws + o_Wb);

    const int EB = (TE + 255) / 256;
    const int NB4 = (N + 3) / 4;

    // ---- CSR by dst ----
    hipMemsetAsync(deg, 0, (size_t)N * 4, stream);
    k_deg<<<EB, 256, 0, stream>>>(ei, deg);
    k_scan1<<<SCAN_B, 256, 0, stream>>>(deg, bsum);
    k_scan2<<<1, 256, 0, stream>>>(bsum, boff, rowp);
    k_scan3<<<SCAN_B, 256, 0, stream>>>(deg, boff, rowp);
    hipMemsetAsync(fill, 0, (size_t)N * 4, stream);
    k_fill<<<EB, 256, 0, stream>>>(ei, rowp, fill, srcc);

    // ---- W bf16 copies (one launch) ----
    k_wb3<<<192, 256, 0, stream>>>(W[0], W[1], W[2], Wb);

    // ---- 3 GAT layers ----
    for (int l = 0; l < 3; l++) {
        const float* Xin = (l == 0) ? x : Ob;
        k_gemm<<<GEMM_B, 256, 0, stream>>>(Xin, Wb + l * 16384, Hb16, att[l], ai, aj, ss, l > 0 ? 1 : 0);
        hipMemsetAsync(den, 0, (size_t)N * 4, stream);
        k_edge_soft<<<NB4, 256, 0, stream>>>(rowp, srcc, ai, aj, alpha, den);
        k_invden<<<SCAN_B, 256, 0, stream>>>(den, inv);
        k_aggregate<<<NB4, 256, 0, stream>>>(rowp, srcc, alpha, inv, Hu, bb[l], Ob);
        hipMemsetAsync(csum, 0, 256 * 4, stream);            // colsum + colsq
        k_stats<<<256, 256, 0, stream>>>(Ob, csum, csq);
        k_bnfinal<<<1, 128, 0, stream>>>(csum, csq, gg[l], be[l], ss);
    }

    // ---- decoder ----
    k_T<<<32, 256, 0, stream>>>(P1, P2, Tm);
    k_M<<<64, 256, 0, stream>>>(Tm, P1, Mm);
    k_pred<<<1024, 128, 0, stream>>>(Ob, ss, drug, Mm, (float*)d_out);
}